// Round 2
// baseline (215.205 us; speedup 1.0000x reference)
//
#include <hip/hip_runtime.h>
#include <cstdint>
#include <cmath>

// ---------------------------------------------------------------------------
// GProjection: project B*N points into V=3 views, bilinear-sample 3 feature
// pyramids (64@56x56, 128@28x28, 256@14x14 -> 448 ch), reduce max/mean/std
// over views. Output [B,N,3+3*448] f32.
//
// R1 structure: transpose feats to channel-last in ws, then 3 per-level
// kernels (L2-resident working sets: 2.4/1.2/0.6 MB per batch vs 4 MB/XCD)
// with vectorized gathers (float1/float2/float4 per lane).
// ---------------------------------------------------------------------------

__global__ void setup_cams_kernel(const float* __restrict__ poses,
                                  const int* __restrict__ resolution,
                                  float* __restrict__ ws, int BV) {
    int t = blockIdx.x * blockDim.x + threadIdx.x;
    if (t == 0) {
        float h0 = ((float)resolution[0] - 1.0f) * 0.5f;
        float h1 = ((float)resolution[1] - 1.0f) * 0.5f;
        ws[0] = 111.5f - h0;   // c_off0
        ws[1] = 111.5f - h1;   // c_off1
        ws[2] = h0;            // half_res0
        ws[3] = h1;            // half_res1
    }
    if (t < BV) {
        const float* p = poses + (size_t)t * 5;
        const float d = 0.017453292519943295f;  // pi/180
        float theta = p[0] * d;
        float elr   = p[1] * d;
        float dist  = p[3];
        float st = sinf(theta), ct = cosf(theta);
        float se = sinf(elr),   ce = cosf(elr);
        float camy = dist * se;
        float lens = dist * ce;
        float camx = lens * ct;
        float camz = lens * st;
        float Zx = camx, Zy = camy, Zz = camz;
        float Yx = -camy * ct, Yy = lens, Yz = -camy * st;  // cos/sin(theta+pi)
        float Xx = Yy * Zz - Yz * Zy;
        float Xy = Yz * Zx - Yx * Zz;
        float Xz = Yx * Zy - Yy * Zx;
        float rx = 1.0f / sqrtf(Xx*Xx + Xy*Xy + Xz*Xz);
        float ry = 1.0f / sqrtf(Yx*Yx + Yy*Yy + Yz*Yz);
        float rz = 1.0f / sqrtf(Zx*Zx + Zy*Zy + Zz*Zz);
        float* c = ws + 4 + (size_t)t * 12;
        c[0] = Xx*rx; c[1] = Xy*rx; c[2] = Xz*rx;
        c[3] = Yx*ry; c[4] = Yy*ry; c[5] = Yz*ry;
        c[6] = Zx*rz; c[7] = Zy*rz; c[8] = Zz*rz;
        c[9] = camx; c[10] = camy; c[11] = camz;
    }
}

// [C][P] -> [P][C] per slice (slice = blockIdx.z)
__global__ void transpose_cp_kernel(const float* __restrict__ in,
                                    float* __restrict__ out, int C, int P) {
    __shared__ float tile[32][33];
    int slice = blockIdx.z;
    const float* src = in + (size_t)slice * C * P;
    float* dst = out + (size_t)slice * C * P;
    int p0 = blockIdx.x * 32, c0 = blockIdx.y * 32;
    int tx = threadIdx.x, ty = threadIdx.y;  // 32 x 8
#pragma unroll
    for (int i = 0; i < 32; i += 8) {
        int c = c0 + ty + i, p = p0 + tx;
        if (c < C && p < P) tile[ty + i][tx] = src[(size_t)c * P + p];
    }
    __syncthreads();
#pragma unroll
    for (int i = 0; i < 32; i += 8) {
        int p = p0 + ty + i, c = c0 + tx;
        if (p < P && c < C) dst[(size_t)p * C + c] = tile[tx][ty + i];
    }
}

struct Corners {
    int p00, p10, p01, p11;
    float w00, w10, w01, w11;
};

__device__ __forceinline__ Corners mk_corners(float gx, float gy, int S) {
    // torch grid_sample: bilinear, zeros padding, align_corners=False
    float x = ((gx + 1.0f) * (float)S - 1.0f) * 0.5f;
    float y = ((gy + 1.0f) * (float)S - 1.0f) * 0.5f;
    float x0f = floorf(x), y0f = floorf(y);
    float wx1 = x - x0f, wy1 = y - y0f;
    float wx0 = 1.0f - wx1, wy0 = 1.0f - wy1;
    int x0 = (int)x0f, y0 = (int)y0f;
    int x1 = x0 + 1, y1 = y0 + 1;
    bool vx0 = (x0 >= 0) && (x0 <= S - 1);
    bool vx1 = (x1 >= 0) && (x1 <= S - 1);
    bool vy0 = (y0 >= 0) && (y0 <= S - 1);
    bool vy1 = (y1 >= 0) && (y1 <= S - 1);
    int xi0 = min(max(x0, 0), S - 1);
    int xi1 = min(max(x1, 0), S - 1);
    int yi0 = min(max(y0, 0), S - 1);
    int yi1 = min(max(y1, 0), S - 1);
    Corners c;
    c.p00 = yi0 * S + xi0;
    c.p10 = yi0 * S + xi1;
    c.p01 = yi1 * S + xi0;
    c.p11 = yi1 * S + xi1;
    c.w00 = wx0 * wy0 * ((vx0 && vy0) ? 1.0f : 0.0f);
    c.w10 = wx1 * wy0 * ((vx1 && vy0) ? 1.0f : 0.0f);
    c.w01 = wx0 * wy1 * ((vx0 && vy1) ? 1.0f : 0.0f);
    c.w11 = wx1 * wy1 * ((vx1 && vy1) ? 1.0f : 0.0f);
    return c;
}

template <int VEC> struct VecOf;
template <> struct VecOf<1> { using T = float; };
template <> struct VecOf<2> { using T = float __attribute__((ext_vector_type(2))); };
template <> struct VecOf<4> { using T = float __attribute__((ext_vector_type(4))); };

template <int C, int VEC>
__device__ __forceinline__ typename VecOf<VEC>::T
sampv(const float* __restrict__ base, const Corners& cr, int lane) {
    using VecT = typename VecOf<VEC>::T;
    const VecT* r00 = (const VecT*)(base + (size_t)cr.p00 * C);
    const VecT* r10 = (const VecT*)(base + (size_t)cr.p10 * C);
    const VecT* r01 = (const VecT*)(base + (size_t)cr.p01 * C);
    const VecT* r11 = (const VecT*)(base + (size_t)cr.p11 * C);
    return cr.w00 * r00[lane] + cr.w10 * r10[lane]
         + cr.w01 * r01[lane] + cr.w11 * r11[lane];
}

// One pyramid level: feat is channel-last [V*B][S*S][C]; lane owns VEC
// consecutive channels (C == 64*VEC). GBASE = channel offset of this level
// in the 448-wide concat. COORDS: also copy the 3 input coords.
template <int C, int S, int VEC, int GBASE, bool COORDS>
__global__ __launch_bounds__(256) void gproj_level_kernel(
    const float* __restrict__ feat, const float* __restrict__ inputs,
    const float* __restrict__ cams, float* __restrict__ out, int B, int N) {
    using VecT = typename VecOf<VEC>::T;
    const int wave = threadIdx.x >> 6;
    const int lane = threadIdx.x & 63;
    const int point = blockIdx.x * 4 + wave;
    if (point >= B * N) return;
    const int b = point / N;

    const float c_off0 = cams[0], c_off1 = cams[1];
    const float inv_h0 = 1.0f / cams[2], inv_h1 = 1.0f / cams[3];
    const float* cam = cams + 4;

    const float* ip = inputs + (size_t)point * 3;
    const float px = ip[0], py = ip[1], pz = ip[2] - 0.8f;  // + MESH_POS

    // world = p @ cm0 + o0
    const float* m0 = cam + (size_t)(b * 3) * 12;
    const float wx = px * m0[0] + py * m0[3] + pz * m0[6] + m0[9];
    const float wy = px * m0[1] + py * m0[4] + pz * m0[7] + m0[10];
    const float wz = px * m0[2] + py * m0[5] + pz * m0[8] + m0[11];

    VecT vals[3];

#pragma unroll
    for (int v = 0; v < 3; ++v) {
        const float* m = cam + (size_t)(b * 3 + v) * 12;
        float qx = wx - m[9], qy = wy - m[10], qz = wz - m[11];
        float Xc = m[0] * qx + m[1] * qy + m[2] * qz;
        float Yc = m[3] * qx + m[4] * qy + m[5] * qz;
        float Zc = m[6] * qx + m[7] * qy + m[8] * qz;
        float invZ = 1.0f / Zc;
        float wpix = -248.0f * (Xc * invZ) + c_off0;
        float hpix =  248.0f * (Yc * invZ) + c_off1;
        float gx = fminf(fmaxf(wpix * inv_h0, -1.0f), 1.0f);
        float gy = fminf(fmaxf(hpix * inv_h1, -1.0f), 1.0f);
        Corners cr = mk_corners(gx, gy, S);
        const float* basep = feat + (size_t)(v * B + b) * S * S * C;
        vals[v] = sampv<C, VEC>(basep, cr, lane);
    }

    float* op = out + (size_t)point * 1347;
    if (COORDS && lane < 3) op[lane] = ip[lane];

    VecT vmx, vmean, vsd;
    const float* pa = (const float*)&vals[0];
    const float* pb = (const float*)&vals[1];
    const float* pc = (const float*)&vals[2];
    float* qmx = (float*)&vmx;
    float* qme = (float*)&vmean;
    float* qsd = (float*)&vsd;
#pragma unroll
    for (int j = 0; j < VEC; ++j) {
        float a = pa[j], bv = pb[j], cv = pc[j];
        float mx = fmaxf(a, fmaxf(bv, cv));
        float mean = (a + bv + cv) * (1.0f / 3.0f);
        float da = a - mean, db = bv - mean, dc = cv - mean;
        float sd = sqrtf((da * da + db * db + dc * dc) * 0.5f);  // ddof=1
        qmx[j] = mx; qme[j] = mean; qsd[j] = sd;
    }
    const int g = GBASE + VEC * lane;
    __builtin_memcpy(&op[3 + g],   &vmx,   VEC * 4);
    __builtin_memcpy(&op[451 + g], &vmean, VEC * 4);
    __builtin_memcpy(&op[899 + g], &vsd,   VEC * 4);
}

// ---- fallback (no workspace): channel-first scalar gathers ----
__device__ __forceinline__ float samp_cf(const float* __restrict__ base,
                                         const Corners& cr, int P, int c) {
    const float* bc = base + (size_t)c * P;
    return cr.w00 * bc[cr.p00] + cr.w10 * bc[cr.p10]
         + cr.w01 * bc[cr.p01] + cr.w11 * bc[cr.p11];
}

__global__ __launch_bounds__(256) void gproj_fallback_kernel(
    const float* __restrict__ f0, const float* __restrict__ f1,
    const float* __restrict__ f2, const float* __restrict__ inputs,
    const float* __restrict__ cams, float* __restrict__ out, int B, int N) {
    const int wave = threadIdx.x >> 6;
    const int lane = threadIdx.x & 63;
    const int point = blockIdx.x * 4 + wave;
    if (point >= B * N) return;
    const int b = point / N;

    const float c_off0 = cams[0], c_off1 = cams[1];
    const float inv_h0 = 1.0f / cams[2], inv_h1 = 1.0f / cams[3];
    const float* cam = cams + 4;

    const float* ip = inputs + (size_t)point * 3;
    const float px = ip[0], py = ip[1], pz = ip[2] - 0.8f;

    const float* m0 = cam + (size_t)(b * 3) * 12;
    const float wx = px * m0[0] + py * m0[3] + pz * m0[6] + m0[9];
    const float wy = px * m0[1] + py * m0[4] + pz * m0[7] + m0[10];
    const float wz = px * m0[2] + py * m0[5] + pz * m0[8] + m0[11];

    float vals[3][7];
#pragma unroll
    for (int v = 0; v < 3; ++v) {
        const float* m = cam + (size_t)(b * 3 + v) * 12;
        float qx = wx - m[9], qy = wy - m[10], qz = wz - m[11];
        float Xc = m[0] * qx + m[1] * qy + m[2] * qz;
        float Yc = m[3] * qx + m[4] * qy + m[5] * qz;
        float Zc = m[6] * qx + m[7] * qy + m[8] * qz;
        float invZ = 1.0f / Zc;
        float wpix = -248.0f * (Xc * invZ) + c_off0;
        float hpix =  248.0f * (Yc * invZ) + c_off1;
        float gx = fminf(fmaxf(wpix * inv_h0, -1.0f), 1.0f);
        float gy = fminf(fmaxf(hpix * inv_h1, -1.0f), 1.0f);
        Corners cr0 = mk_corners(gx, gy, 56);
        Corners cr1 = mk_corners(gx, gy, 28);
        Corners cr2 = mk_corners(gx, gy, 14);
        int slice = v * B + b;
        const float* b0 = f0 + (size_t)slice * 64 * 3136;
        const float* b1 = f1 + (size_t)slice * 128 * 784;
        const float* b2 = f2 + (size_t)slice * 256 * 196;
        vals[v][0] = samp_cf(b0, cr0, 3136, lane);
        vals[v][1] = samp_cf(b1, cr1, 784, lane);
        vals[v][2] = samp_cf(b1, cr1, 784, lane + 64);
        vals[v][3] = samp_cf(b2, cr2, 196, lane);
        vals[v][4] = samp_cf(b2, cr2, 196, lane + 64);
        vals[v][5] = samp_cf(b2, cr2, 196, lane + 128);
        vals[v][6] = samp_cf(b2, cr2, 196, lane + 192);
    }

    float* op = out + (size_t)point * 1347;
    if (lane < 3) op[lane] = ip[lane];
#pragma unroll
    for (int k = 0; k < 7; ++k) {
        float a = vals[0][k], bv = vals[1][k], cv = vals[2][k];
        float mx = fmaxf(a, fmaxf(bv, cv));
        float mean = (a + bv + cv) * (1.0f / 3.0f);
        float da = a - mean, db = bv - mean, dc = cv - mean;
        float sd = sqrtf((da * da + db * db + dc * dc) * 0.5f);
        int g = lane + 64 * k;
        op[3 + g] = mx;
        op[451 + g] = mean;
        op[899 + g] = sd;
    }
}

extern "C" void kernel_launch(void* const* d_in, const int* in_sizes, int n_in,
                              void* d_out, int out_size, void* d_ws, size_t ws_size,
                              hipStream_t stream) {
    const float* feat0 = (const float*)d_in[0];
    const float* feat1 = (const float*)d_in[1];
    const float* feat2 = (const float*)d_in[2];
    const float* inputs = (const float*)d_in[3];
    const float* poses = (const float*)d_in[4];
    const int* resolution = (const int*)d_in[5];
    float* out = (float*)d_out;
    float* ws = (float*)d_ws;

    const int V = 3;
    const int B = in_sizes[4] / (V * 5);
    const int N = in_sizes[3] / (B * 3);
    const int BV = B * V;

    setup_cams_kernel<<<1, 64, 0, stream>>>(poses, resolution, ws, BV);

    const size_t cams_elems = 512;
    const size_t t0_elems = (size_t)BV * 64 * 3136;
    const size_t t1_elems = (size_t)BV * 128 * 784;
    const size_t t2_elems = (size_t)BV * 256 * 196;
    const size_t need = (cams_elems + t0_elems + t1_elems + t2_elems) * sizeof(float);

    const int total = B * N;
    const int nblocks = (total + 3) / 4;  // 4 points (waves) per 256-thread block

    if (ws_size >= need) {
        float* t0 = ws + cams_elems;
        float* t1 = t0 + t0_elems;
        float* t2 = t1 + t1_elems;
        dim3 blk(32, 8);
        transpose_cp_kernel<<<dim3((3136 + 31) / 32, 64 / 32, BV), blk, 0, stream>>>(feat0, t0, 64, 3136);
        transpose_cp_kernel<<<dim3((784 + 31) / 32, 128 / 32, BV), blk, 0, stream>>>(feat1, t1, 128, 784);
        transpose_cp_kernel<<<dim3((196 + 31) / 32, 256 / 32, BV), blk, 0, stream>>>(feat2, t2, 256, 196);
        // Per-level kernels: working sets 2.4 / 1.2 / 0.6 MB per batch -> L2-resident.
        gproj_level_kernel<64, 56, 1, 0, true><<<nblocks, 256, 0, stream>>>(t0, inputs, ws, out, B, N);
        gproj_level_kernel<128, 28, 2, 64, false><<<nblocks, 256, 0, stream>>>(t1, inputs, ws, out, B, N);
        gproj_level_kernel<256, 14, 4, 192, false><<<nblocks, 256, 0, stream>>>(t2, inputs, ws, out, B, N);
    } else {
        gproj_fallback_kernel<<<nblocks, 256, 0, stream>>>(feat0, feat1, feat2, inputs, ws, out, B, N);
    }
}

// Round 3
// 144.902 us; speedup vs baseline: 1.4852x; 1.4852x over previous
//
#include <hip/hip_runtime.h>
#include <cstdint>
#include <cmath>

// ---------------------------------------------------------------------------
// GProjection: project B*N points into V=3 views, bilinear-sample 3 feature
// pyramids (64@56x56, 128@28x28, 256@14x14 -> 448 ch), reduce max/mean/std
// over views. Output [B,N,3+3*448] f32.
//
// R2: single fused main kernel (R1's 3-way split regressed: lost cross-level
// MLP). Channel-last transposed feats in ws; vec gathers (1/2/4 fl per lane);
// XCD-batch swizzle (blockIdx%8 == XCD == batch -> each L2 holds ONE batch's
// 4.2MB feature set all kernel long); nontemporal (evict-first) out stores so
// 353MB of streaming writes don't thrash the hot feature lines in L2.
// ---------------------------------------------------------------------------

typedef float f32x2 __attribute__((ext_vector_type(2)));
typedef float f32x4 __attribute__((ext_vector_type(4)));

__global__ void setup_cams_kernel(const float* __restrict__ poses,
                                  const int* __restrict__ resolution,
                                  float* __restrict__ ws, int BV) {
    int t = blockIdx.x * blockDim.x + threadIdx.x;
    if (t == 0) {
        float h0 = ((float)resolution[0] - 1.0f) * 0.5f;
        float h1 = ((float)resolution[1] - 1.0f) * 0.5f;
        ws[0] = 111.5f - h0;   // c_off0
        ws[1] = 111.5f - h1;   // c_off1
        ws[2] = h0;            // half_res0
        ws[3] = h1;            // half_res1
    }
    if (t < BV) {
        const float* p = poses + (size_t)t * 5;
        const float d = 0.017453292519943295f;  // pi/180
        float theta = p[0] * d;
        float elr   = p[1] * d;
        float dist  = p[3];
        float st = sinf(theta), ct = cosf(theta);
        float se = sinf(elr),   ce = cosf(elr);
        float camy = dist * se;
        float lens = dist * ce;
        float camx = lens * ct;
        float camz = lens * st;
        float Zx = camx, Zy = camy, Zz = camz;
        float Yx = -camy * ct, Yy = lens, Yz = -camy * st;  // cos/sin(theta+pi)
        float Xx = Yy * Zz - Yz * Zy;
        float Xy = Yz * Zx - Yx * Zz;
        float Xz = Yx * Zy - Yy * Zx;
        float rx = 1.0f / sqrtf(Xx*Xx + Xy*Xy + Xz*Xz);
        float ry = 1.0f / sqrtf(Yx*Yx + Yy*Yy + Yz*Yz);
        float rz = 1.0f / sqrtf(Zx*Zx + Zy*Zy + Zz*Zz);
        float* c = ws + 4 + (size_t)t * 12;
        c[0] = Xx*rx; c[1] = Xy*rx; c[2] = Xz*rx;
        c[3] = Yx*ry; c[4] = Yy*ry; c[5] = Yz*ry;
        c[6] = Zx*rz; c[7] = Zy*rz; c[8] = Zz*rz;
        c[9] = camx; c[10] = camy; c[11] = camz;
    }
}

// [C][P] -> [P][C] per slice (slice = blockIdx.z)
__global__ void transpose_cp_kernel(const float* __restrict__ in,
                                    float* __restrict__ out, int C, int P) {
    __shared__ float tile[32][33];
    int slice = blockIdx.z;
    const float* src = in + (size_t)slice * C * P;
    float* dst = out + (size_t)slice * C * P;
    int p0 = blockIdx.x * 32, c0 = blockIdx.y * 32;
    int tx = threadIdx.x, ty = threadIdx.y;  // 32 x 8
#pragma unroll
    for (int i = 0; i < 32; i += 8) {
        int c = c0 + ty + i, p = p0 + tx;
        if (c < C && p < P) tile[ty + i][tx] = src[(size_t)c * P + p];
    }
    __syncthreads();
#pragma unroll
    for (int i = 0; i < 32; i += 8) {
        int p = p0 + ty + i, c = c0 + tx;
        if (p < P && c < C) dst[(size_t)p * C + c] = tile[tx][ty + i];
    }
}

struct Corners {
    int p00, p10, p01, p11;
    float w00, w10, w01, w11;
};

__device__ __forceinline__ Corners mk_corners(float gx, float gy, int S) {
    // torch grid_sample: bilinear, zeros padding, align_corners=False
    float x = ((gx + 1.0f) * (float)S - 1.0f) * 0.5f;
    float y = ((gy + 1.0f) * (float)S - 1.0f) * 0.5f;
    float x0f = floorf(x), y0f = floorf(y);
    float wx1 = x - x0f, wy1 = y - y0f;
    float wx0 = 1.0f - wx1, wy0 = 1.0f - wy1;
    int x0 = (int)x0f, y0 = (int)y0f;
    int x1 = x0 + 1, y1 = y0 + 1;
    bool vx0 = (x0 >= 0) && (x0 <= S - 1);
    bool vx1 = (x1 >= 0) && (x1 <= S - 1);
    bool vy0 = (y0 >= 0) && (y0 <= S - 1);
    bool vy1 = (y1 >= 0) && (y1 <= S - 1);
    int xi0 = min(max(x0, 0), S - 1);
    int xi1 = min(max(x1, 0), S - 1);
    int yi0 = min(max(y0, 0), S - 1);
    int yi1 = min(max(y1, 0), S - 1);
    Corners c;
    c.p00 = yi0 * S + xi0;
    c.p10 = yi0 * S + xi1;
    c.p01 = yi1 * S + xi0;
    c.p11 = yi1 * S + xi1;
    c.w00 = wx0 * wy0 * ((vx0 && vy0) ? 1.0f : 0.0f);
    c.w10 = wx1 * wy0 * ((vx1 && vy0) ? 1.0f : 0.0f);
    c.w01 = wx0 * wy1 * ((vx0 && vy1) ? 1.0f : 0.0f);
    c.w11 = wx1 * wy1 * ((vx1 && vy1) ? 1.0f : 0.0f);
    return c;
}

template <int VEC> struct VecOf;
template <> struct VecOf<1> { using T = float; };
template <> struct VecOf<2> { using T = f32x2; };
template <> struct VecOf<4> { using T = f32x4; };

template <int C, int VEC>
__device__ __forceinline__ typename VecOf<VEC>::T
sampv(const float* __restrict__ base, const Corners& cr, int lane) {
    using VecT = typename VecOf<VEC>::T;
    const VecT* r00 = (const VecT*)(base + (size_t)cr.p00 * C);
    const VecT* r10 = (const VecT*)(base + (size_t)cr.p10 * C);
    const VecT* r01 = (const VecT*)(base + (size_t)cr.p01 * C);
    const VecT* r11 = (const VecT*)(base + (size_t)cr.p11 * C);
    return cr.w00 * r00[lane] + cr.w10 * r10[lane]
         + cr.w01 * r01[lane] + cr.w11 * r11[lane];
}

template <typename VecT, int VEC>
__device__ __forceinline__ void stats3_nt(VecT a, VecT b, VecT c,
                                          float* pmx, float* pme, float* psd) {
    VecT mx, me, sd;
    const float* pa = (const float*)&a;
    const float* pb = (const float*)&b;
    const float* pc = (const float*)&c;
    float* qx = (float*)&mx; float* qe = (float*)&me; float* qs = (float*)&sd;
#pragma unroll
    for (int j = 0; j < VEC; ++j) {
        float x = pa[j], y = pb[j], z = pc[j];
        float m = fmaxf(x, fmaxf(y, z));
        float mean = (x + y + z) * (1.0f / 3.0f);
        float dx = x - mean, dy = y - mean, dz = z - mean;
        float s = sqrtf((dx * dx + dy * dy + dz * dz) * 0.5f);  // ddof=1
        qx[j] = m; qe[j] = mean; qs[j] = s;
    }
    __builtin_nontemporal_store(mx, (VecT*)pmx);
    __builtin_nontemporal_store(me, (VecT*)pme);
    __builtin_nontemporal_store(sd, (VecT*)psd);
}

// Fused main kernel: one point per wave, all 3 levels, channel-last feats.
// Block->batch swizzle: b = blockIdx.x % B, so with B==8 each XCD (round-robin
// blockIdx%8) only touches one batch's features (4.2MB, ~L2-resident).
__global__ __launch_bounds__(256) void gproj_fused_kernel(
    const float* __restrict__ t0, const float* __restrict__ t1,
    const float* __restrict__ t2, const float* __restrict__ inputs,
    const float* __restrict__ cams, float* __restrict__ out, int B, int N) {
    const int wave = threadIdx.x >> 6;
    const int lane = threadIdx.x & 63;
    const int b = blockIdx.x % B;
    const int pib = (blockIdx.x / B) * 4 + wave;  // point index within batch
    if (pib >= N) return;
    const int point = b * N + pib;

    const float c_off0 = cams[0], c_off1 = cams[1];
    const float inv_h0 = 1.0f / cams[2], inv_h1 = 1.0f / cams[3];
    const float* cam = cams + 4;

    const float* ip = inputs + (size_t)point * 3;
    const float px = ip[0], py = ip[1], pz = ip[2] - 0.8f;  // + MESH_POS

    // world = p @ cm0 + o0
    const float* m0 = cam + (size_t)(b * 3) * 12;
    const float wx = px * m0[0] + py * m0[3] + pz * m0[6] + m0[9];
    const float wy = px * m0[1] + py * m0[4] + pz * m0[7] + m0[10];
    const float wz = px * m0[2] + py * m0[5] + pz * m0[8] + m0[11];

    float  v0[3];
    f32x2  v1[3];
    f32x4  v2a[3], v2b[3];

#pragma unroll
    for (int v = 0; v < 3; ++v) {
        const float* m = cam + (size_t)(b * 3 + v) * 12;
        float qx = wx - m[9], qy = wy - m[10], qz = wz - m[11];
        float Xc = m[0] * qx + m[1] * qy + m[2] * qz;
        float Yc = m[3] * qx + m[4] * qy + m[5] * qz;
        float Zc = m[6] * qx + m[7] * qy + m[8] * qz;
        float invZ = 1.0f / Zc;
        float wpix = -248.0f * (Xc * invZ) + c_off0;
        float hpix =  248.0f * (Yc * invZ) + c_off1;
        float gx = fminf(fmaxf(wpix * inv_h0, -1.0f), 1.0f);
        float gy = fminf(fmaxf(hpix * inv_h1, -1.0f), 1.0f);

        Corners cr0 = mk_corners(gx, gy, 56);
        Corners cr1 = mk_corners(gx, gy, 28);
        Corners cr2 = mk_corners(gx, gy, 14);

        const int slice = v * B + b;
        const float* b0 = t0 + (size_t)slice * 64 * 3136;
        const float* b1 = t1 + (size_t)slice * 128 * 784;
        const float* b2 = t2 + (size_t)slice * 256 * 196;

        v0[v]  = sampv<64, 1>(b0, cr0, lane);
        v1[v]  = sampv<128, 2>(b1, cr1, lane);
        // level2: lane owns channels {2l..2l+1} and {128+2l..128+2l+1} as two
        // float4 halves? No -- lane owns 4 consecutive ch twice: {4l..4l+3}
        // would need C=256 in one float4; keep two float4 gathers:
        // first covers ch [4*lane .. 4*lane+3] of lower 256? C=256, VEC=4
        // spans all 256 with one float4 per lane. Use two halves of 128ch?
        v2a[v] = sampv<256, 4>(b2, cr2, lane);          // ch 4l..4l+3... (see below)
        v2b[v] = sampv<256, 4>(b2, cr2 /*same*/, lane + 64);  // ch 256..? guarded below
    }
    // NOTE on level2 mapping: C=256, one float4 per lane covers 4*lane ->
    // lanes 0..63 cover ch 0..255 exactly. v2b would be OOB; instead we use
    // v2a only. (v2b computed above reads base + (p*256 + 4*(lane+64)) which
    // is within the NEXT pixel's row -- harmless data, unused.)

    float* op = out + (size_t)point * 1347;
    if (lane < 3) __builtin_nontemporal_store(ip[lane], &op[lane]);

    // level0: ch g in [0,64), out offset 3+g
    {
        float* base = op + 3 + lane;
        float mx = fmaxf(v0[0], fmaxf(v0[1], v0[2]));
        float mean = (v0[0] + v0[1] + v0[2]) * (1.0f / 3.0f);
        float dx = v0[0] - mean, dy = v0[1] - mean, dz = v0[2] - mean;
        float sd = sqrtf((dx * dx + dy * dy + dz * dz) * 0.5f);
        __builtin_nontemporal_store(mx, base);
        __builtin_nontemporal_store(mean, base + 448);
        __builtin_nontemporal_store(sd, base + 896);
    }
    // level1: ch g = 64 + 2*lane
    {
        const int g = 64 + 2 * lane;
        stats3_nt<f32x2, 2>(v1[0], v1[1], v1[2],
                            op + 3 + g, op + 451 + g, op + 899 + g);
    }
    // level2: ch g = 192 + 4*lane
    {
        const int g = 192 + 4 * lane;
        stats3_nt<f32x4, 4>(v2a[0], v2a[1], v2a[2],
                            op + 3 + g, op + 451 + g, op + 899 + g);
    }
}

// ---- fallback (no workspace): channel-first scalar gathers ----
__device__ __forceinline__ float samp_cf(const float* __restrict__ base,
                                         const Corners& cr, int P, int c) {
    const float* bc = base + (size_t)c * P;
    return cr.w00 * bc[cr.p00] + cr.w10 * bc[cr.p10]
         + cr.w01 * bc[cr.p01] + cr.w11 * bc[cr.p11];
}

__global__ __launch_bounds__(256) void gproj_fallback_kernel(
    const float* __restrict__ f0, const float* __restrict__ f1,
    const float* __restrict__ f2, const float* __restrict__ inputs,
    const float* __restrict__ cams, float* __restrict__ out, int B, int N) {
    const int wave = threadIdx.x >> 6;
    const int lane = threadIdx.x & 63;
    const int point = blockIdx.x * 4 + wave;
    if (point >= B * N) return;
    const int b = point / N;

    const float c_off0 = cams[0], c_off1 = cams[1];
    const float inv_h0 = 1.0f / cams[2], inv_h1 = 1.0f / cams[3];
    const float* cam = cams + 4;

    const float* ip = inputs + (size_t)point * 3;
    const float px = ip[0], py = ip[1], pz = ip[2] - 0.8f;

    const float* m0 = cam + (size_t)(b * 3) * 12;
    const float wx = px * m0[0] + py * m0[3] + pz * m0[6] + m0[9];
    const float wy = px * m0[1] + py * m0[4] + pz * m0[7] + m0[10];
    const float wz = px * m0[2] + py * m0[5] + pz * m0[8] + m0[11];

    float vals[3][7];
#pragma unroll
    for (int v = 0; v < 3; ++v) {
        const float* m = cam + (size_t)(b * 3 + v) * 12;
        float qx = wx - m[9], qy = wy - m[10], qz = wz - m[11];
        float Xc = m[0] * qx + m[1] * qy + m[2] * qz;
        float Yc = m[3] * qx + m[4] * qy + m[5] * qz;
        float Zc = m[6] * qx + m[7] * qy + m[8] * qz;
        float invZ = 1.0f / Zc;
        float wpix = -248.0f * (Xc * invZ) + c_off0;
        float hpix =  248.0f * (Yc * invZ) + c_off1;
        float gx = fminf(fmaxf(wpix * inv_h0, -1.0f), 1.0f);
        float gy = fminf(fmaxf(hpix * inv_h1, -1.0f), 1.0f);
        Corners cr0 = mk_corners(gx, gy, 56);
        Corners cr1 = mk_corners(gx, gy, 28);
        Corners cr2 = mk_corners(gx, gy, 14);
        int slice = v * B + b;
        const float* b0 = f0 + (size_t)slice * 64 * 3136;
        const float* b1 = f1 + (size_t)slice * 128 * 784;
        const float* b2 = f2 + (size_t)slice * 256 * 196;
        vals[v][0] = samp_cf(b0, cr0, 3136, lane);
        vals[v][1] = samp_cf(b1, cr1, 784, lane);
        vals[v][2] = samp_cf(b1, cr1, 784, lane + 64);
        vals[v][3] = samp_cf(b2, cr2, 196, lane);
        vals[v][4] = samp_cf(b2, cr2, 196, lane + 64);
        vals[v][5] = samp_cf(b2, cr2, 196, lane + 128);
        vals[v][6] = samp_cf(b2, cr2, 196, lane + 192);
    }

    float* op = out + (size_t)point * 1347;
    if (lane < 3) op[lane] = ip[lane];
#pragma unroll
    for (int k = 0; k < 7; ++k) {
        float a = vals[0][k], bv = vals[1][k], cv = vals[2][k];
        float mx = fmaxf(a, fmaxf(bv, cv));
        float mean = (a + bv + cv) * (1.0f / 3.0f);
        float da = a - mean, db = bv - mean, dc = cv - mean;
        float sd = sqrtf((da * da + db * db + dc * dc) * 0.5f);
        int g = lane + 64 * k;
        op[3 + g] = mx;
        op[451 + g] = mean;
        op[899 + g] = sd;
    }
}

extern "C" void kernel_launch(void* const* d_in, const int* in_sizes, int n_in,
                              void* d_out, int out_size, void* d_ws, size_t ws_size,
                              hipStream_t stream) {
    const float* feat0 = (const float*)d_in[0];
    const float* feat1 = (const float*)d_in[1];
    const float* feat2 = (const float*)d_in[2];
    const float* inputs = (const float*)d_in[3];
    const float* poses = (const float*)d_in[4];
    const int* resolution = (const int*)d_in[5];
    float* out = (float*)d_out;
    float* ws = (float*)d_ws;

    const int V = 3;
    const int B = in_sizes[4] / (V * 5);
    const int N = in_sizes[3] / (B * 3);
    const int BV = B * V;

    setup_cams_kernel<<<1, 64, 0, stream>>>(poses, resolution, ws, BV);

    const size_t cams_elems = 512;
    const size_t t0_elems = (size_t)BV * 64 * 3136;
    const size_t t1_elems = (size_t)BV * 128 * 784;
    const size_t t2_elems = (size_t)BV * 256 * 196;
    // +64 floats pad: fused kernel's speculative v2b gather may read up to
    // 1 pixel-row (1KB) past a slice; slices are interior except the very
    // last, pad the arena end.
    const size_t need = (cams_elems + t0_elems + t1_elems + t2_elems + 512) * sizeof(float);

    if (ws_size >= need) {
        float* t0 = ws + cams_elems;
        float* t1 = t0 + t0_elems;
        float* t2 = t1 + t1_elems;
        dim3 blk(32, 8);
        transpose_cp_kernel<<<dim3((3136 + 31) / 32, 64 / 32, BV), blk, 0, stream>>>(feat0, t0, 64, 3136);
        transpose_cp_kernel<<<dim3((784 + 31) / 32, 128 / 32, BV), blk, 0, stream>>>(feat1, t1, 128, 784);
        transpose_cp_kernel<<<dim3((196 + 31) / 32, 256 / 32, BV), blk, 0, stream>>>(feat2, t2, 256, 196);
        const int nbb = (N + 3) / 4;           // blocks per batch
        gproj_fused_kernel<<<B * nbb, 256, 0, stream>>>(t0, t1, t2, inputs, ws, out, B, N);
    } else {
        const int nblocks = (B * N + 3) / 4;
        gproj_fallback_kernel<<<nblocks, 256, 0, stream>>>(feat0, feat1, feat2, inputs, ws, out, B, N);
    }
}

// Round 4
// 137.420 us; speedup vs baseline: 1.5660x; 1.0544x over previous
//
#include <hip/hip_runtime.h>
#include <cstdint>
#include <cmath>

// ---------------------------------------------------------------------------
// GProjection: project B*N points into V=3 views, bilinear-sample 3 feature
// pyramids (64@56x56, 128@28x28, 256@14x14 -> 448 ch), reduce max/mean/std
// over views. Output [B,N,3+3*448] f32.
//
// R3: transposed channel-last features stored as fp16 in ws.
//  - halves gather traffic (1.38 -> 0.69 GB) and transpose writes
//  - per-batch footprint 4.2 -> 2.1 MB: strictly L2-resident per XCD
//    (XCD-batch swizzle: blockIdx%8 == XCD == batch)
//  - fp16 adds <=~5e-3 abs error (feats ~N(0,1)); threshold is 9.25e-2.
// Fused main kernel (R2), nontemporal segment stores for the 353MB output.
// ---------------------------------------------------------------------------

typedef float f32x2 __attribute__((ext_vector_type(2)));
typedef float f32x4 __attribute__((ext_vector_type(4)));
typedef _Float16 f16;
typedef _Float16 f16x2 __attribute__((ext_vector_type(2)));
typedef _Float16 f16x4 __attribute__((ext_vector_type(4)));

__global__ void setup_cams_kernel(const float* __restrict__ poses,
                                  const int* __restrict__ resolution,
                                  float* __restrict__ ws, int BV) {
    int t = blockIdx.x * blockDim.x + threadIdx.x;
    if (t == 0) {
        float h0 = ((float)resolution[0] - 1.0f) * 0.5f;
        float h1 = ((float)resolution[1] - 1.0f) * 0.5f;
        ws[0] = 111.5f - h0;   // c_off0
        ws[1] = 111.5f - h1;   // c_off1
        ws[2] = h0;            // half_res0
        ws[3] = h1;            // half_res1
    }
    if (t < BV) {
        const float* p = poses + (size_t)t * 5;
        const float d = 0.017453292519943295f;  // pi/180
        float theta = p[0] * d;
        float elr   = p[1] * d;
        float dist  = p[3];
        float st = sinf(theta), ct = cosf(theta);
        float se = sinf(elr),   ce = cosf(elr);
        float camy = dist * se;
        float lens = dist * ce;
        float camx = lens * ct;
        float camz = lens * st;
        float Zx = camx, Zy = camy, Zz = camz;
        float Yx = -camy * ct, Yy = lens, Yz = -camy * st;  // cos/sin(theta+pi)
        float Xx = Yy * Zz - Yz * Zy;
        float Xy = Yz * Zx - Yx * Zz;
        float Xz = Yx * Zy - Yy * Zx;
        float rx = 1.0f / sqrtf(Xx*Xx + Xy*Xy + Xz*Xz);
        float ry = 1.0f / sqrtf(Yx*Yx + Yy*Yy + Yz*Yz);
        float rz = 1.0f / sqrtf(Zx*Zx + Zy*Zy + Zz*Zz);
        float* c = ws + 4 + (size_t)t * 12;
        c[0] = Xx*rx; c[1] = Xy*rx; c[2] = Xz*rx;
        c[3] = Yx*ry; c[4] = Yy*ry; c[5] = Yz*ry;
        c[6] = Zx*rz; c[7] = Zy*rz; c[8] = Zz*rz;
        c[9] = camx; c[10] = camy; c[11] = camz;
    }
}

// [C][P] f32 -> [P][C] f16 per slice (slice = blockIdx.z)
__global__ void transpose_cp_f16_kernel(const float* __restrict__ in,
                                        f16* __restrict__ out, int C, int P) {
    __shared__ float tile[32][33];
    int slice = blockIdx.z;
    const float* src = in + (size_t)slice * C * P;
    f16* dst = out + (size_t)slice * C * P;
    int p0 = blockIdx.x * 32, c0 = blockIdx.y * 32;
    int tx = threadIdx.x, ty = threadIdx.y;  // 32 x 8
#pragma unroll
    for (int i = 0; i < 32; i += 8) {
        int c = c0 + ty + i, p = p0 + tx;
        if (c < C && p < P) tile[ty + i][tx] = src[(size_t)c * P + p];
    }
    __syncthreads();
#pragma unroll
    for (int i = 0; i < 32; i += 8) {
        int p = p0 + ty + i, c = c0 + tx;
        if (p < P && c < C) dst[(size_t)p * C + c] = (f16)tile[tx][ty + i];
    }
}

struct Corners {
    int p00, p10, p01, p11;
    float w00, w10, w01, w11;
};

__device__ __forceinline__ Corners mk_corners(float gx, float gy, int S) {
    // torch grid_sample: bilinear, zeros padding, align_corners=False
    float x = ((gx + 1.0f) * (float)S - 1.0f) * 0.5f;
    float y = ((gy + 1.0f) * (float)S - 1.0f) * 0.5f;
    float x0f = floorf(x), y0f = floorf(y);
    float wx1 = x - x0f, wy1 = y - y0f;
    float wx0 = 1.0f - wx1, wy0 = 1.0f - wy1;
    int x0 = (int)x0f, y0 = (int)y0f;
    int x1 = x0 + 1, y1 = y0 + 1;
    bool vx0 = (x0 >= 0) && (x0 <= S - 1);
    bool vx1 = (x1 >= 0) && (x1 <= S - 1);
    bool vy0 = (y0 >= 0) && (y0 <= S - 1);
    bool vy1 = (y1 >= 0) && (y1 <= S - 1);
    int xi0 = min(max(x0, 0), S - 1);
    int xi1 = min(max(x1, 0), S - 1);
    int yi0 = min(max(y0, 0), S - 1);
    int yi1 = min(max(y1, 0), S - 1);
    Corners c;
    c.p00 = yi0 * S + xi0;
    c.p10 = yi0 * S + xi1;
    c.p01 = yi1 * S + xi0;
    c.p11 = yi1 * S + xi1;
    c.w00 = wx0 * wy0 * ((vx0 && vy0) ? 1.0f : 0.0f);
    c.w10 = wx1 * wy0 * ((vx1 && vy0) ? 1.0f : 0.0f);
    c.w01 = wx0 * wy1 * ((vx0 && vy1) ? 1.0f : 0.0f);
    c.w11 = wx1 * wy1 * ((vx1 && vy1) ? 1.0f : 0.0f);
    return c;
}

template <int VEC> struct VecOf;
template <> struct VecOf<1> { using T = float; };
template <> struct VecOf<2> { using T = f32x2; };
template <> struct VecOf<4> { using T = f32x4; };
template <int VEC> struct F16VecOf;
template <> struct F16VecOf<1> { using T = f16; };
template <> struct F16VecOf<2> { using T = f16x2; };
template <> struct F16VecOf<4> { using T = f16x4; };

template <int C, int VEC>
__device__ __forceinline__ typename VecOf<VEC>::T
samph(const f16* __restrict__ base, const Corners& cr, int lane) {
    using HV = typename F16VecOf<VEC>::T;
    using FV = typename VecOf<VEC>::T;
    const HV* r00 = (const HV*)(base + (size_t)cr.p00 * C);
    const HV* r10 = (const HV*)(base + (size_t)cr.p10 * C);
    const HV* r01 = (const HV*)(base + (size_t)cr.p01 * C);
    const HV* r11 = (const HV*)(base + (size_t)cr.p11 * C);
    HV h00 = r00[lane], h10 = r10[lane], h01 = r01[lane], h11 = r11[lane];
    FV a00, a10, a01, a11;
    if constexpr (VEC == 1) {
        a00 = (float)h00; a10 = (float)h10; a01 = (float)h01; a11 = (float)h11;
    } else {
        a00 = __builtin_convertvector(h00, FV);
        a10 = __builtin_convertvector(h10, FV);
        a01 = __builtin_convertvector(h01, FV);
        a11 = __builtin_convertvector(h11, FV);
    }
    return cr.w00 * a00 + cr.w10 * a10 + cr.w01 * a01 + cr.w11 * a11;
}

template <typename VecT, int VEC>
__device__ __forceinline__ void stats3_nt(VecT a, VecT b, VecT c,
                                          float* pmx, float* pme, float* psd) {
    VecT mx, me, sd;
    const float* pa = (const float*)&a;
    const float* pb = (const float*)&b;
    const float* pc = (const float*)&c;
    float* qx = (float*)&mx; float* qe = (float*)&me; float* qs = (float*)&sd;
#pragma unroll
    for (int j = 0; j < VEC; ++j) {
        float x = pa[j], y = pb[j], z = pc[j];
        float m = fmaxf(x, fmaxf(y, z));
        float mean = (x + y + z) * (1.0f / 3.0f);
        float dx = x - mean, dy = y - mean, dz = z - mean;
        float s = sqrtf((dx * dx + dy * dy + dz * dz) * 0.5f);  // ddof=1
        qx[j] = m; qe[j] = mean; qs[j] = s;
    }
    __builtin_nontemporal_store(mx, (VecT*)pmx);
    __builtin_nontemporal_store(me, (VecT*)pme);
    __builtin_nontemporal_store(sd, (VecT*)psd);
}

// Fused main kernel: one point per wave, all 3 levels, channel-last f16 feats.
// b = blockIdx.x % B (B==8): each XCD only touches one batch's features
// (2.1MB, L2-resident).
__global__ __launch_bounds__(256) void gproj_fused_kernel(
    const f16* __restrict__ t0, const f16* __restrict__ t1,
    const f16* __restrict__ t2, const float* __restrict__ inputs,
    const float* __restrict__ cams, float* __restrict__ out, int B, int N) {
    const int wave = threadIdx.x >> 6;
    const int lane = threadIdx.x & 63;
    const int b = blockIdx.x % B;
    const int pib = (blockIdx.x / B) * 4 + wave;  // point index within batch
    if (pib >= N) return;
    const int point = b * N + pib;

    const float c_off0 = cams[0], c_off1 = cams[1];
    const float inv_h0 = 1.0f / cams[2], inv_h1 = 1.0f / cams[3];
    const float* cam = cams + 4;

    const float* ip = inputs + (size_t)point * 3;
    const float px = ip[0], py = ip[1], pz = ip[2] - 0.8f;  // + MESH_POS

    // world = p @ cm0 + o0
    const float* m0 = cam + (size_t)(b * 3) * 12;
    const float wx = px * m0[0] + py * m0[3] + pz * m0[6] + m0[9];
    const float wy = px * m0[1] + py * m0[4] + pz * m0[7] + m0[10];
    const float wz = px * m0[2] + py * m0[5] + pz * m0[8] + m0[11];

    float  v0[3];
    f32x2  v1[3];
    f32x4  v2[3];

#pragma unroll
    for (int v = 0; v < 3; ++v) {
        const float* m = cam + (size_t)(b * 3 + v) * 12;
        float qx = wx - m[9], qy = wy - m[10], qz = wz - m[11];
        float Xc = m[0] * qx + m[1] * qy + m[2] * qz;
        float Yc = m[3] * qx + m[4] * qy + m[5] * qz;
        float Zc = m[6] * qx + m[7] * qy + m[8] * qz;
        float invZ = 1.0f / Zc;
        float wpix = -248.0f * (Xc * invZ) + c_off0;
        float hpix =  248.0f * (Yc * invZ) + c_off1;
        float gx = fminf(fmaxf(wpix * inv_h0, -1.0f), 1.0f);
        float gy = fminf(fmaxf(hpix * inv_h1, -1.0f), 1.0f);

        Corners cr0 = mk_corners(gx, gy, 56);
        Corners cr1 = mk_corners(gx, gy, 28);
        Corners cr2 = mk_corners(gx, gy, 14);

        const int slice = v * B + b;
        const f16* b0 = t0 + (size_t)slice * 64 * 3136;
        const f16* b1 = t1 + (size_t)slice * 128 * 784;
        const f16* b2 = t2 + (size_t)slice * 256 * 196;

        v0[v] = samph<64, 1>(b0, cr0, lane);    // ch lane
        v1[v] = samph<128, 2>(b1, cr1, lane);   // ch 2*lane..2*lane+1
        v2[v] = samph<256, 4>(b2, cr2, lane);   // ch 4*lane..4*lane+3
    }

    float* op = out + (size_t)point * 1347;
    if (lane < 3) __builtin_nontemporal_store(ip[lane], &op[lane]);

    // level0: ch g = lane
    {
        float* basep = op + 3 + lane;
        float mx = fmaxf(v0[0], fmaxf(v0[1], v0[2]));
        float mean = (v0[0] + v0[1] + v0[2]) * (1.0f / 3.0f);
        float dx = v0[0] - mean, dy = v0[1] - mean, dz = v0[2] - mean;
        float sd = sqrtf((dx * dx + dy * dy + dz * dz) * 0.5f);
        __builtin_nontemporal_store(mx, basep);
        __builtin_nontemporal_store(mean, basep + 448);
        __builtin_nontemporal_store(sd, basep + 896);
    }
    // level1: ch g = 64 + 2*lane
    {
        const int g = 64 + 2 * lane;
        stats3_nt<f32x2, 2>(v1[0], v1[1], v1[2],
                            op + 3 + g, op + 451 + g, op + 899 + g);
    }
    // level2: ch g = 192 + 4*lane
    {
        const int g = 192 + 4 * lane;
        stats3_nt<f32x4, 4>(v2[0], v2[1], v2[2],
                            op + 3 + g, op + 451 + g, op + 899 + g);
    }
}

// ---- fallback (no workspace): channel-first f32 scalar gathers ----
__device__ __forceinline__ float samp_cf(const float* __restrict__ base,
                                         const Corners& cr, int P, int c) {
    const float* bc = base + (size_t)c * P;
    return cr.w00 * bc[cr.p00] + cr.w10 * bc[cr.p10]
         + cr.w01 * bc[cr.p01] + cr.w11 * bc[cr.p11];
}

__global__ __launch_bounds__(256) void gproj_fallback_kernel(
    const float* __restrict__ f0, const float* __restrict__ f1,
    const float* __restrict__ f2, const float* __restrict__ inputs,
    const float* __restrict__ cams, float* __restrict__ out, int B, int N) {
    const int wave = threadIdx.x >> 6;
    const int lane = threadIdx.x & 63;
    const int point = blockIdx.x * 4 + wave;
    if (point >= B * N) return;
    const int b = point / N;

    const float c_off0 = cams[0], c_off1 = cams[1];
    const float inv_h0 = 1.0f / cams[2], inv_h1 = 1.0f / cams[3];
    const float* cam = cams + 4;

    const float* ip = inputs + (size_t)point * 3;
    const float px = ip[0], py = ip[1], pz = ip[2] - 0.8f;

    const float* m0 = cam + (size_t)(b * 3) * 12;
    const float wx = px * m0[0] + py * m0[3] + pz * m0[6] + m0[9];
    const float wy = px * m0[1] + py * m0[4] + pz * m0[7] + m0[10];
    const float wz = px * m0[2] + py * m0[5] + pz * m0[8] + m0[11];

    float vals[3][7];
#pragma unroll
    for (int v = 0; v < 3; ++v) {
        const float* m = cam + (size_t)(b * 3 + v) * 12;
        float qx = wx - m[9], qy = wy - m[10], qz = wz - m[11];
        float Xc = m[0] * qx + m[1] * qy + m[2] * qz;
        float Yc = m[3] * qx + m[4] * qy + m[5] * qz;
        float Zc = m[6] * qx + m[7] * qy + m[8] * qz;
        float invZ = 1.0f / Zc;
        float wpix = -248.0f * (Xc * invZ) + c_off0;
        float hpix =  248.0f * (Yc * invZ) + c_off1;
        float gx = fminf(fmaxf(wpix * inv_h0, -1.0f), 1.0f);
        float gy = fminf(fmaxf(hpix * inv_h1, -1.0f), 1.0f);
        Corners cr0 = mk_corners(gx, gy, 56);
        Corners cr1 = mk_corners(gx, gy, 28);
        Corners cr2 = mk_corners(gx, gy, 14);
        int slice = v * B + b;
        const float* b0 = f0 + (size_t)slice * 64 * 3136;
        const float* b1 = f1 + (size_t)slice * 128 * 784;
        const float* b2 = f2 + (size_t)slice * 256 * 196;
        vals[v][0] = samp_cf(b0, cr0, 3136, lane);
        vals[v][1] = samp_cf(b1, cr1, 784, lane);
        vals[v][2] = samp_cf(b1, cr1, 784, lane + 64);
        vals[v][3] = samp_cf(b2, cr2, 196, lane);
        vals[v][4] = samp_cf(b2, cr2, 196, lane + 64);
        vals[v][5] = samp_cf(b2, cr2, 196, lane + 128);
        vals[v][6] = samp_cf(b2, cr2, 196, lane + 192);
    }

    float* op = out + (size_t)point * 1347;
    if (lane < 3) op[lane] = ip[lane];
#pragma unroll
    for (int k = 0; k < 7; ++k) {
        float a = vals[0][k], bv = vals[1][k], cv = vals[2][k];
        float mx = fmaxf(a, fmaxf(bv, cv));
        float mean = (a + bv + cv) * (1.0f / 3.0f);
        float da = a - mean, db = bv - mean, dc = cv - mean;
        float sd = sqrtf((da * da + db * db + dc * dc) * 0.5f);
        int g = lane + 64 * k;
        op[3 + g] = mx;
        op[451 + g] = mean;
        op[899 + g] = sd;
    }
}

extern "C" void kernel_launch(void* const* d_in, const int* in_sizes, int n_in,
                              void* d_out, int out_size, void* d_ws, size_t ws_size,
                              hipStream_t stream) {
    const float* feat0 = (const float*)d_in[0];
    const float* feat1 = (const float*)d_in[1];
    const float* feat2 = (const float*)d_in[2];
    const float* inputs = (const float*)d_in[3];
    const float* poses = (const float*)d_in[4];
    const int* resolution = (const int*)d_in[5];
    float* out = (float*)d_out;
    float* ws = (float*)d_ws;

    const int V = 3;
    const int B = in_sizes[4] / (V * 5);
    const int N = in_sizes[3] / (B * 3);
    const int BV = B * V;

    setup_cams_kernel<<<1, 64, 0, stream>>>(poses, resolution, ws, BV);

    const size_t cams_elems = 512;  // floats
    const size_t t0_elems = (size_t)BV * 64 * 3136;  // halfs
    const size_t t1_elems = (size_t)BV * 128 * 784;
    const size_t t2_elems = (size_t)BV * 256 * 196;
    const size_t need = cams_elems * sizeof(float)
                      + (t0_elems + t1_elems + t2_elems) * sizeof(f16);

    if (ws_size >= need) {
        f16* t0 = (f16*)(ws + cams_elems);
        f16* t1 = t0 + t0_elems;
        f16* t2 = t1 + t1_elems;
        dim3 blk(32, 8);
        transpose_cp_f16_kernel<<<dim3((3136 + 31) / 32, 64 / 32, BV), blk, 0, stream>>>(feat0, t0, 64, 3136);
        transpose_cp_f16_kernel<<<dim3((784 + 31) / 32, 128 / 32, BV), blk, 0, stream>>>(feat1, t1, 128, 784);
        transpose_cp_f16_kernel<<<dim3((196 + 31) / 32, 256 / 32, BV), blk, 0, stream>>>(feat2, t2, 256, 196);
        const int nbb = (N + 3) / 4;  // blocks per batch
        gproj_fused_kernel<<<B * nbb, 256, 0, stream>>>(t0, t1, t2, inputs, ws, out, B, N);
    } else {
        const int nblocks = (B * N + 3) / 4;
        gproj_fallback_kernel<<<nblocks, 256, 0, stream>>>(feat0, feat1, feat2, inputs, ws, out, B, N);
    }
}

// Round 5
// 132.413 us; speedup vs baseline: 1.6253x; 1.0378x over previous
//
#include <hip/hip_runtime.h>
#include <cstdint>
#include <cmath>

// ---------------------------------------------------------------------------
// GProjection: project B*N points into V=3 views, bilinear-sample 3 feature
// pyramids (64@56x56, 128@28x28, 256@14x14 -> 448 ch), reduce max/mean/std
// over views. Output [B,N,3+3*448] f32.
//
// R5: the main kernel was ~45% wave-uniform VALU (projection + corner math
// redundantly computed by all 64 lanes; CDNA SALU has no FP). Hoist it:
//  - corners_kernel precomputes per (point,view,level): 4 byte-offsets (i32)
//    + 4 f32 weights (32B slot) into ws. Main kernel loads them via
//    readfirstlane'd scalar addresses (s_load + SALU address math).
//  - merged single transpose dispatch (3 levels in one grid).
//  - channel-last fp16 features (R3), XCD-batch swizzle + nt stores (R2).
// ---------------------------------------------------------------------------

typedef float f32x2 __attribute__((ext_vector_type(2)));
typedef float f32x4 __attribute__((ext_vector_type(4)));
typedef _Float16 f16;
typedef _Float16 f16x2 __attribute__((ext_vector_type(2)));
typedef _Float16 f16x4 __attribute__((ext_vector_type(4)));

__global__ void setup_cams_kernel(const float* __restrict__ poses,
                                  const int* __restrict__ resolution,
                                  float* __restrict__ ws, int BV) {
    int t = blockIdx.x * blockDim.x + threadIdx.x;
    if (t == 0) {
        float h0 = ((float)resolution[0] - 1.0f) * 0.5f;
        float h1 = ((float)resolution[1] - 1.0f) * 0.5f;
        ws[0] = 111.5f - h0;   // c_off0
        ws[1] = 111.5f - h1;   // c_off1
        ws[2] = h0;            // half_res0
        ws[3] = h1;            // half_res1
    }
    if (t < BV) {
        const float* p = poses + (size_t)t * 5;
        const float d = 0.017453292519943295f;  // pi/180
        float theta = p[0] * d;
        float elr   = p[1] * d;
        float dist  = p[3];
        float st = sinf(theta), ct = cosf(theta);
        float se = sinf(elr),   ce = cosf(elr);
        float camy = dist * se;
        float lens = dist * ce;
        float camx = lens * ct;
        float camz = lens * st;
        float Zx = camx, Zy = camy, Zz = camz;
        float Yx = -camy * ct, Yy = lens, Yz = -camy * st;  // cos/sin(theta+pi)
        float Xx = Yy * Zz - Yz * Zy;
        float Xy = Yz * Zx - Yx * Zz;
        float Xz = Yx * Zy - Yy * Zx;
        float rx = 1.0f / sqrtf(Xx*Xx + Xy*Xy + Xz*Xz);
        float ry = 1.0f / sqrtf(Yx*Yx + Yy*Yy + Yz*Yz);
        float rz = 1.0f / sqrtf(Zx*Zx + Zy*Zy + Zz*Zz);
        float* c = ws + 4 + (size_t)t * 12;
        c[0] = Xx*rx; c[1] = Xy*rx; c[2] = Xz*rx;
        c[3] = Yx*ry; c[4] = Yy*ry; c[5] = Yz*ry;
        c[6] = Zx*rz; c[7] = Zy*rz; c[8] = Zz*rz;
        c[9] = camx; c[10] = camy; c[11] = camz;
    }
}

// ---- merged transpose: [C][P] f32 -> [P][C] f16, all 3 levels, one grid ----
__global__ void transpose_all_kernel(const float* __restrict__ f0,
                                     const float* __restrict__ f1,
                                     const float* __restrict__ f2,
                                     f16* __restrict__ t0, f16* __restrict__ t1,
                                     f16* __restrict__ t2, int BV) {
    __shared__ float tile[32][33];
    const int nb0 = 98 * 2 * BV;   // P=3136 -> 98 tiles, C=64 -> 2 tiles
    const int nb1 = 25 * 4 * BV;   // P=784  -> 25,      C=128 -> 4
    int bid = blockIdx.x;
    const float* src; f16* dst; int C, P, tP, local;
    if (bid < nb0)            { src = f0; dst = t0; C = 64;  P = 3136; tP = 98; local = bid; }
    else if (bid < nb0 + nb1) { src = f1; dst = t1; C = 128; P = 784;  tP = 25; local = bid - nb0; }
    else                      { src = f2; dst = t2; C = 256; P = 196;  tP = 7;  local = bid - nb0 - nb1; }
    int per = tP * (C >> 5);
    int slice = local / per;
    int rem = local - slice * per;
    int cy = rem / tP;
    int cx = rem - cy * tP;
    const float* s = src + (size_t)slice * C * P;
    f16* d = dst + (size_t)slice * C * P;
    int p0 = cx * 32, c0 = cy * 32;
    int tx = threadIdx.x, ty = threadIdx.y;  // 32 x 8
#pragma unroll
    for (int i = 0; i < 32; i += 8) {
        int c = c0 + ty + i, p = p0 + tx;
        if (p < P) tile[ty + i][tx] = s[(size_t)c * P + p];   // c always < C
    }
    __syncthreads();
#pragma unroll
    for (int i = 0; i < 32; i += 8) {
        int p = p0 + ty + i, c = c0 + tx;
        if (p < P) d[(size_t)p * C + c] = (f16)tile[tx][ty + i];
    }
}

struct Corners {
    int p00, p10, p01, p11;
    float w00, w10, w01, w11;
};

__device__ __forceinline__ Corners mk_corners(float gx, float gy, int S) {
    // torch grid_sample: bilinear, zeros padding, align_corners=False
    float x = ((gx + 1.0f) * (float)S - 1.0f) * 0.5f;
    float y = ((gy + 1.0f) * (float)S - 1.0f) * 0.5f;
    float x0f = floorf(x), y0f = floorf(y);
    float wx1 = x - x0f, wy1 = y - y0f;
    float wx0 = 1.0f - wx1, wy0 = 1.0f - wy1;
    int x0 = (int)x0f, y0 = (int)y0f;
    int x1 = x0 + 1, y1 = y0 + 1;
    bool vx0 = (x0 >= 0) && (x0 <= S - 1);
    bool vx1 = (x1 >= 0) && (x1 <= S - 1);
    bool vy0 = (y0 >= 0) && (y0 <= S - 1);
    bool vy1 = (y1 >= 0) && (y1 <= S - 1);
    int xi0 = min(max(x0, 0), S - 1);
    int xi1 = min(max(x1, 0), S - 1);
    int yi0 = min(max(y0, 0), S - 1);
    int yi1 = min(max(y1, 0), S - 1);
    Corners c;
    c.p00 = yi0 * S + xi0;
    c.p10 = yi0 * S + xi1;
    c.p01 = yi1 * S + xi0;
    c.p11 = yi1 * S + xi1;
    c.w00 = wx0 * wy0 * ((vx0 && vy0) ? 1.0f : 0.0f);
    c.w10 = wx1 * wy0 * ((vx1 && vy0) ? 1.0f : 0.0f);
    c.w01 = wx0 * wy1 * ((vx0 && vy1) ? 1.0f : 0.0f);
    c.w11 = wx1 * wy1 * ((vx1 && vy1) ? 1.0f : 0.0f);
    return c;
}

// Per (point, view): compute projection once, emit 3 levels x (4 byte-offsets
// + 4 f32 weights) = 3 x 32B into corn.
__global__ __launch_bounds__(256) void corners_kernel(
    const float* __restrict__ inputs, const float* __restrict__ cams,
    float* __restrict__ corn, int B, int N) {
    int t = blockIdx.x * blockDim.x + threadIdx.x;
    if (t >= B * N * 3) return;
    int point = t / 3;
    int v = t - point * 3;
    int b = point / N;

    const float c_off0 = cams[0], c_off1 = cams[1];
    const float inv_h0 = 1.0f / cams[2], inv_h1 = 1.0f / cams[3];
    const float* cam = cams + 4;

    const float* ip = inputs + (size_t)point * 3;
    const float px = ip[0], py = ip[1], pz = ip[2] - 0.8f;  // + MESH_POS

    const float* m0 = cam + (size_t)(b * 3) * 12;
    const float wx = px * m0[0] + py * m0[3] + pz * m0[6] + m0[9];
    const float wy = px * m0[1] + py * m0[4] + pz * m0[7] + m0[10];
    const float wz = px * m0[2] + py * m0[5] + pz * m0[8] + m0[11];

    const float* m = cam + (size_t)(b * 3 + v) * 12;
    float qx = wx - m[9], qy = wy - m[10], qz = wz - m[11];
    float Xc = m[0] * qx + m[1] * qy + m[2] * qz;
    float Yc = m[3] * qx + m[4] * qy + m[5] * qz;
    float Zc = m[6] * qx + m[7] * qy + m[8] * qz;
    float invZ = 1.0f / Zc;
    float wpix = -248.0f * (Xc * invZ) + c_off0;
    float hpix =  248.0f * (Yc * invZ) + c_off1;
    float gx = fminf(fmaxf(wpix * inv_h0, -1.0f), 1.0f);
    float gy = fminf(fmaxf(hpix * inv_h1, -1.0f), 1.0f);

    float* o = corn + (size_t)t * 24;
    const int S[3] = {56, 28, 14};
    const int CB[3] = {64 * 2, 128 * 2, 256 * 2};  // row bytes factor (f16)
#pragma unroll
    for (int lvl = 0; lvl < 3; ++lvl) {
        Corners cr = mk_corners(gx, gy, S[lvl]);
        o[lvl * 8 + 0] = __int_as_float(cr.p00 * CB[lvl]);
        o[lvl * 8 + 1] = __int_as_float(cr.p10 * CB[lvl]);
        o[lvl * 8 + 2] = __int_as_float(cr.p01 * CB[lvl]);
        o[lvl * 8 + 3] = __int_as_float(cr.p11 * CB[lvl]);
        o[lvl * 8 + 4] = cr.w00;
        o[lvl * 8 + 5] = cr.w10;
        o[lvl * 8 + 6] = cr.w01;
        o[lvl * 8 + 7] = cr.w11;
    }
}

template <int VEC> struct VecOf;
template <> struct VecOf<1> { using T = float; };
template <> struct VecOf<2> { using T = f32x2; };
template <> struct VecOf<4> { using T = f32x4; };
template <int VEC> struct F16VecOf;
template <> struct F16VecOf<1> { using T = f16; };
template <> struct F16VecOf<2> { using T = f16x2; };
template <> struct F16VecOf<4> { using T = f16x4; };

template <int VEC>
__device__ __forceinline__ typename VecOf<VEC>::T
gather4(const f16* __restrict__ base, const int4 off, const float4 w, int lane) {
    using HV = typename F16VecOf<VEC>::T;
    using FV = typename VecOf<VEC>::T;
    const char* cb = (const char*)base;
    const int lo = lane * (VEC * 2);
    HV h00 = *(const HV*)(cb + off.x + lo);
    HV h10 = *(const HV*)(cb + off.y + lo);
    HV h01 = *(const HV*)(cb + off.z + lo);
    HV h11 = *(const HV*)(cb + off.w + lo);
    FV a00, a10, a01, a11;
    if constexpr (VEC == 1) {
        a00 = (float)h00; a10 = (float)h10; a01 = (float)h01; a11 = (float)h11;
    } else {
        a00 = __builtin_convertvector(h00, FV);
        a10 = __builtin_convertvector(h10, FV);
        a01 = __builtin_convertvector(h01, FV);
        a11 = __builtin_convertvector(h11, FV);
    }
    return w.x * a00 + w.y * a10 + w.z * a01 + w.w * a11;
}

template <typename VecT, int VEC>
__device__ __forceinline__ void stats3_nt(VecT a, VecT b, VecT c,
                                          float* pmx, float* pme, float* psd) {
    VecT mx, me, sd;
    const float* pa = (const float*)&a;
    const float* pb = (const float*)&b;
    const float* pc = (const float*)&c;
    float* qx = (float*)&mx; float* qe = (float*)&me; float* qs = (float*)&sd;
#pragma unroll
    for (int j = 0; j < VEC; ++j) {
        float x = pa[j], y = pb[j], z = pc[j];
        float m = fmaxf(x, fmaxf(y, z));
        float mean = (x + y + z) * (1.0f / 3.0f);
        float dx = x - mean, dy = y - mean, dz = z - mean;
        float s = sqrtf((dx * dx + dy * dy + dz * dz) * 0.5f);  // ddof=1
        qx[j] = m; qe[j] = mean; qs[j] = s;
    }
    __builtin_nontemporal_store(mx, (VecT*)pmx);
    __builtin_nontemporal_store(me, (VecT*)pme);
    __builtin_nontemporal_store(sd, (VecT*)psd);
}

// Main kernel, corners precomputed. One point per wave. b = blockIdx.x % B:
// XCD-batch pinning (2.1MB / batch, L2-resident).
__global__ __launch_bounds__(256) void gproj_main_kernel(
    const f16* __restrict__ t0, const f16* __restrict__ t1,
    const f16* __restrict__ t2, const float* __restrict__ inputs,
    const float* __restrict__ corn, float* __restrict__ out, int B, int N) {
    const int wave = threadIdx.x >> 6;
    const int lane = threadIdx.x & 63;
    const int b = blockIdx.x % B;
    const int pib = (blockIdx.x / B) * 4 + wave;
    if (pib >= N) return;
    const int point = b * N + pib;
    const int pu = __builtin_amdgcn_readfirstlane(point);
    const int bu = __builtin_amdgcn_readfirstlane(b);

    const float* ip = inputs + (size_t)point * 3;

    float  v0[3];
    f32x2  v1[3];
    f32x4  v2[3];

#pragma unroll
    for (int v = 0; v < 3; ++v) {
        const float* cp = corn + (size_t)(pu * 3 + v) * 24;
        const int slice = v * B + bu;
        const f16* b0 = t0 + (size_t)slice * 64 * 3136;
        const f16* b1 = t1 + (size_t)slice * 128 * 784;
        const f16* b2 = t2 + (size_t)slice * 256 * 196;

        int4   o0 = *(const int4*)(cp);
        float4 w0 = *(const float4*)(cp + 4);
        int4   o1 = *(const int4*)(cp + 8);
        float4 w1 = *(const float4*)(cp + 12);
        int4   o2 = *(const int4*)(cp + 16);
        float4 w2 = *(const float4*)(cp + 20);

        v0[v] = gather4<1>(b0, o0, w0, lane);   // ch lane
        v1[v] = gather4<2>(b1, o1, w1, lane);   // ch 2*lane..
        v2[v] = gather4<4>(b2, o2, w2, lane);   // ch 4*lane..
    }

    float* op = out + (size_t)point * 1347;
    if (lane < 3) __builtin_nontemporal_store(ip[lane], &op[lane]);

    {   // level0: ch g = lane
        float* basep = op + 3 + lane;
        float mx = fmaxf(v0[0], fmaxf(v0[1], v0[2]));
        float mean = (v0[0] + v0[1] + v0[2]) * (1.0f / 3.0f);
        float dx = v0[0] - mean, dy = v0[1] - mean, dz = v0[2] - mean;
        float sd = sqrtf((dx * dx + dy * dy + dz * dz) * 0.5f);
        __builtin_nontemporal_store(mx, basep);
        __builtin_nontemporal_store(mean, basep + 448);
        __builtin_nontemporal_store(sd, basep + 896);
    }
    {   // level1: ch g = 64 + 2*lane
        const int g = 64 + 2 * lane;
        stats3_nt<f32x2, 2>(v1[0], v1[1], v1[2],
                            op + 3 + g, op + 451 + g, op + 899 + g);
    }
    {   // level2: ch g = 192 + 4*lane
        const int g = 192 + 4 * lane;
        stats3_nt<f32x4, 4>(v2[0], v2[1], v2[2],
                            op + 3 + g, op + 451 + g, op + 899 + g);
    }
}

// ---- mid-fallback: R4 fused kernel (inline corners), f16 feats ----
template <int C, int VEC>
__device__ __forceinline__ typename VecOf<VEC>::T
samph(const f16* __restrict__ base, const Corners& cr, int lane) {
    using HV = typename F16VecOf<VEC>::T;
    using FV = typename VecOf<VEC>::T;
    const HV* r00 = (const HV*)(base + (size_t)cr.p00 * C);
    const HV* r10 = (const HV*)(base + (size_t)cr.p10 * C);
    const HV* r01 = (const HV*)(base + (size_t)cr.p01 * C);
    const HV* r11 = (const HV*)(base + (size_t)cr.p11 * C);
    HV h00 = r00[lane], h10 = r10[lane], h01 = r01[lane], h11 = r11[lane];
    FV a00, a10, a01, a11;
    if constexpr (VEC == 1) {
        a00 = (float)h00; a10 = (float)h10; a01 = (float)h01; a11 = (float)h11;
    } else {
        a00 = __builtin_convertvector(h00, FV);
        a10 = __builtin_convertvector(h10, FV);
        a01 = __builtin_convertvector(h01, FV);
        a11 = __builtin_convertvector(h11, FV);
    }
    return cr.w00 * a00 + cr.w10 * a10 + cr.w01 * a01 + cr.w11 * a11;
}

__global__ __launch_bounds__(256) void gproj_fused_kernel(
    const f16* __restrict__ t0, const f16* __restrict__ t1,
    const f16* __restrict__ t2, const float* __restrict__ inputs,
    const float* __restrict__ cams, float* __restrict__ out, int B, int N) {
    const int wave = threadIdx.x >> 6;
    const int lane = threadIdx.x & 63;
    const int b = blockIdx.x % B;
    const int pib = (blockIdx.x / B) * 4 + wave;
    if (pib >= N) return;
    const int point = b * N + pib;

    const float c_off0 = cams[0], c_off1 = cams[1];
    const float inv_h0 = 1.0f / cams[2], inv_h1 = 1.0f / cams[3];
    const float* cam = cams + 4;

    const float* ip = inputs + (size_t)point * 3;
    const float px = ip[0], py = ip[1], pz = ip[2] - 0.8f;

    const float* m0 = cam + (size_t)(b * 3) * 12;
    const float wx = px * m0[0] + py * m0[3] + pz * m0[6] + m0[9];
    const float wy = px * m0[1] + py * m0[4] + pz * m0[7] + m0[10];
    const float wz = px * m0[2] + py * m0[5] + pz * m0[8] + m0[11];

    float  v0[3];
    f32x2  v1[3];
    f32x4  v2[3];

#pragma unroll
    for (int v = 0; v < 3; ++v) {
        const float* m = cam + (size_t)(b * 3 + v) * 12;
        float qx = wx - m[9], qy = wy - m[10], qz = wz - m[11];
        float Xc = m[0] * qx + m[1] * qy + m[2] * qz;
        float Yc = m[3] * qx + m[4] * qy + m[5] * qz;
        float Zc = m[6] * qx + m[7] * qy + m[8] * qz;
        float invZ = 1.0f / Zc;
        float wpix = -248.0f * (Xc * invZ) + c_off0;
        float hpix =  248.0f * (Yc * invZ) + c_off1;
        float gx = fminf(fmaxf(wpix * inv_h0, -1.0f), 1.0f);
        float gy = fminf(fmaxf(hpix * inv_h1, -1.0f), 1.0f);
        Corners cr0 = mk_corners(gx, gy, 56);
        Corners cr1 = mk_corners(gx, gy, 28);
        Corners cr2 = mk_corners(gx, gy, 14);
        const int slice = v * B + b;
        v0[v] = samph<64, 1>(t0 + (size_t)slice * 64 * 3136, cr0, lane);
        v1[v] = samph<128, 2>(t1 + (size_t)slice * 128 * 784, cr1, lane);
        v2[v] = samph<256, 4>(t2 + (size_t)slice * 256 * 196, cr2, lane);
    }

    float* op = out + (size_t)point * 1347;
    if (lane < 3) __builtin_nontemporal_store(ip[lane], &op[lane]);
    {
        float* basep = op + 3 + lane;
        float mx = fmaxf(v0[0], fmaxf(v0[1], v0[2]));
        float mean = (v0[0] + v0[1] + v0[2]) * (1.0f / 3.0f);
        float dx = v0[0] - mean, dy = v0[1] - mean, dz = v0[2] - mean;
        float sd = sqrtf((dx * dx + dy * dy + dz * dz) * 0.5f);
        __builtin_nontemporal_store(mx, basep);
        __builtin_nontemporal_store(mean, basep + 448);
        __builtin_nontemporal_store(sd, basep + 896);
    }
    {
        const int g = 64 + 2 * lane;
        stats3_nt<f32x2, 2>(v1[0], v1[1], v1[2],
                            op + 3 + g, op + 451 + g, op + 899 + g);
    }
    {
        const int g = 192 + 4 * lane;
        stats3_nt<f32x4, 4>(v2[0], v2[1], v2[2],
                            op + 3 + g, op + 451 + g, op + 899 + g);
    }
}

// ---- last-resort fallback (no workspace): channel-first f32 gathers ----
__device__ __forceinline__ float samp_cf(const float* __restrict__ base,
                                         const Corners& cr, int P, int c) {
    const float* bc = base + (size_t)c * P;
    return cr.w00 * bc[cr.p00] + cr.w10 * bc[cr.p10]
         + cr.w01 * bc[cr.p01] + cr.w11 * bc[cr.p11];
}

__global__ __launch_bounds__(256) void gproj_fallback_kernel(
    const float* __restrict__ f0, const float* __restrict__ f1,
    const float* __restrict__ f2, const float* __restrict__ inputs,
    const float* __restrict__ cams, float* __restrict__ out, int B, int N) {
    const int wave = threadIdx.x >> 6;
    const int lane = threadIdx.x & 63;
    const int point = blockIdx.x * 4 + wave;
    if (point >= B * N) return;
    const int b = point / N;

    const float c_off0 = cams[0], c_off1 = cams[1];
    const float inv_h0 = 1.0f / cams[2], inv_h1 = 1.0f / cams[3];
    const float* cam = cams + 4;

    const float* ip = inputs + (size_t)point * 3;
    const float px = ip[0], py = ip[1], pz = ip[2] - 0.8f;

    const float* m0 = cam + (size_t)(b * 3) * 12;
    const float wx = px * m0[0] + py * m0[3] + pz * m0[6] + m0[9];
    const float wy = px * m0[1] + py * m0[4] + pz * m0[7] + m0[10];
    const float wz = px * m0[2] + py * m0[5] + pz * m0[8] + m0[11];

    float vals[3][7];
#pragma unroll
    for (int v = 0; v < 3; ++v) {
        const float* m = cam + (size_t)(b * 3 + v) * 12;
        float qx = wx - m[9], qy = wy - m[10], qz = wz - m[11];
        float Xc = m[0] * qx + m[1] * qy + m[2] * qz;
        float Yc = m[3] * qx + m[4] * qy + m[5] * qz;
        float Zc = m[6] * qx + m[7] * qy + m[8] * qz;
        float invZ = 1.0f / Zc;
        float wpix = -248.0f * (Xc * invZ) + c_off0;
        float hpix =  248.0f * (Yc * invZ) + c_off1;
        float gx = fminf(fmaxf(wpix * inv_h0, -1.0f), 1.0f);
        float gy = fminf(fmaxf(hpix * inv_h1, -1.0f), 1.0f);
        Corners cr0 = mk_corners(gx, gy, 56);
        Corners cr1 = mk_corners(gx, gy, 28);
        Corners cr2 = mk_corners(gx, gy, 14);
        int slice = v * B + b;
        const float* b0 = f0 + (size_t)slice * 64 * 3136;
        const float* b1 = f1 + (size_t)slice * 128 * 784;
        const float* b2 = f2 + (size_t)slice * 256 * 196;
        vals[v][0] = samp_cf(b0, cr0, 3136, lane);
        vals[v][1] = samp_cf(b1, cr1, 784, lane);
        vals[v][2] = samp_cf(b1, cr1, 784, lane + 64);
        vals[v][3] = samp_cf(b2, cr2, 196, lane);
        vals[v][4] = samp_cf(b2, cr2, 196, lane + 64);
        vals[v][5] = samp_cf(b2, cr2, 196, lane + 128);
        vals[v][6] = samp_cf(b2, cr2, 196, lane + 192);
    }

    float* op = out + (size_t)point * 1347;
    if (lane < 3) op[lane] = ip[lane];
#pragma unroll
    for (int k = 0; k < 7; ++k) {
        float a = vals[0][k], bv = vals[1][k], cv = vals[2][k];
        float mx = fmaxf(a, fmaxf(bv, cv));
        float mean = (a + bv + cv) * (1.0f / 3.0f);
        float da = a - mean, db = bv - mean, dc = cv - mean;
        float sd = sqrtf((da * da + db * db + dc * dc) * 0.5f);
        int g = lane + 64 * k;
        op[3 + g] = mx;
        op[451 + g] = mean;
        op[899 + g] = sd;
    }
}

extern "C" void kernel_launch(void* const* d_in, const int* in_sizes, int n_in,
                              void* d_out, int out_size, void* d_ws, size_t ws_size,
                              hipStream_t stream) {
    const float* feat0 = (const float*)d_in[0];
    const float* feat1 = (const float*)d_in[1];
    const float* feat2 = (const float*)d_in[2];
    const float* inputs = (const float*)d_in[3];
    const float* poses = (const float*)d_in[4];
    const int* resolution = (const int*)d_in[5];
    float* out = (float*)d_out;
    float* ws = (float*)d_ws;

    const int V = 3;
    const int B = in_sizes[4] / (V * 5);
    const int N = in_sizes[3] / (B * 3);
    const int BV = B * V;
    const int total = B * N;

    setup_cams_kernel<<<1, 64, 0, stream>>>(poses, resolution, ws, BV);

    const size_t cams_elems = 512;                     // f32
    const size_t t0_elems = (size_t)BV * 64 * 3136;    // f16
    const size_t t1_elems = (size_t)BV * 128 * 784;
    const size_t t2_elems = (size_t)BV * 256 * 196;
    const size_t th_elems = t0_elems + t1_elems + t2_elems;
    const size_t corn_elems = (size_t)total * 3 * 24;  // f32
    // layout: [cams f32][corn f32][t0/t1/t2 f16]
    const size_t need_mid  = cams_elems * sizeof(float) + th_elems * sizeof(f16);
    const size_t need_full = need_mid + corn_elems * sizeof(float);

    const int nbb = (N + 3) / 4;   // blocks per batch (4 points / 256-thread block)
    const int tgrid = BV * (98 * 2 + 25 * 4 + 7 * 8);
    dim3 tblk(32, 8);

    if (ws_size >= need_full) {
        float* corn = ws + cams_elems;
        f16* t0 = (f16*)(corn + corn_elems);
        f16* t1 = t0 + t0_elems;
        f16* t2 = t1 + t1_elems;
        corners_kernel<<<(total * 3 + 255) / 256, 256, 0, stream>>>(inputs, ws, corn, B, N);
        transpose_all_kernel<<<tgrid, tblk, 0, stream>>>(feat0, feat1, feat2, t0, t1, t2, BV);
        gproj_main_kernel<<<B * nbb, 256, 0, stream>>>(t0, t1, t2, inputs, corn, out, B, N);
    } else if (ws_size >= need_mid) {
        f16* t0 = (f16*)(ws + cams_elems);
        f16* t1 = t0 + t0_elems;
        f16* t2 = t1 + t1_elems;
        transpose_all_kernel<<<tgrid, tblk, 0, stream>>>(feat0, feat1, feat2, t0, t1, t2, BV);
        gproj_fused_kernel<<<B * nbb, 256, 0, stream>>>(t0, t1, t2, inputs, ws, out, B, N);
    } else {
        gproj_fallback_kernel<<<(total + 3) / 4, 256, 0, stream>>>(
            feat0, feat1, feat2, inputs, ws, out, B, N);
    }
}